// Round 14
// baseline (261.647 us; speedup 1.0000x reference)
//
#include <hip/hip_runtime.h>
#include <math.h>

#define NB 8192     // batch rows
#define DD 512      // hidden dim
#define KC 4096     // codebook size
#define NL 4        // layers

#define NTB 32        // part[] column tiles (128 codes each)
#define MARGIN_I 2048.0f // refine margin, int-sim units (256 x true; >10 sigma of i8 noise)
#define QS 16.0f      // i8 quantization scale

#define GBM 256
#define GBN 256

typedef int    i32x4 __attribute__((ext_vector_type(4)));
typedef unsigned short u16;
typedef unsigned int   u32;
typedef unsigned long long u64;

struct Top2 { float v1; int i1; float v2; int i2; };

__device__ __forceinline__ u32 umaxu(u32 a, u32 b) { return a > b ? a : b; }
__device__ __forceinline__ u32 uminu(u32 a, u32 b) { return a < b ? a : b; }

__device__ __forceinline__ u32 q8(float f) {   // fp32 -> signed i8 (byte), scale QS
    int v = (int)rintf(f * QS);
    v = v < -127 ? -127 : (v > 127 ? 127 : v);
    return (u32)(v & 0xFF);
}

// Fused front-end: blocks [0,4096) convert codebooks fp32->i8 + cbsq partials
// (+ first 64 blocks zero out_usage); blocks [4096,6144) convert x -> residq.
// One launch instead of two serialized ones.
__global__ __launch_bounds__(256)
void k_cvt_all(const float* __restrict__ x, const float* __restrict__ cb,
               u64* __restrict__ residq, u64* __restrict__ cbq,
               double* __restrict__ cq, float* __restrict__ usage)
{
    const int bid = blockIdx.x;
    if (bid < 4096) {
        __shared__ double red[256];
        const int i = bid * 256 + threadIdx.x;
        if (bid < 64) {   // 64*256 threads x 4 floats = 65536 = NL*KC
            const float4 z = {0.f, 0.f, 0.f, 0.f};
            ((float4*)usage)[i] = z;
        }
        const float4 a = ((const float4*)cb)[i * 2];
        const float4 b = ((const float4*)cb)[i * 2 + 1];
        u64 p = (u64)(q8(a.x) | (q8(a.y) << 8) | (q8(a.z) << 16) | (q8(a.w) << 24))
              | ((u64)(q8(b.x) | (q8(b.y) << 8) | (q8(b.z) << 16) | (q8(b.w) << 24)) << 32);
        cbq[i] = p;
        red[threadIdx.x] = (double)a.x * a.x + (double)a.y * a.y + (double)a.z * a.z
                         + (double)a.w * a.w + (double)b.x * b.x + (double)b.y * b.y
                         + (double)b.z * b.z + (double)b.w * b.w;
        __syncthreads();
        for (int st = 128; st > 0; st >>= 1) {
            if (threadIdx.x < st) red[threadIdx.x] += red[threadIdx.x + st];
            __syncthreads();
        }
        if (threadIdx.x == 0) cq[bid] = red[0];
    } else {
        const int i = (bid - 4096) * 256 + threadIdx.x;   // exact: NB*DD/8 = 524288
        const float4 a = ((const float4*)x)[i * 2];
        const float4 b = ((const float4*)x)[i * 2 + 1];
        u64 p = (u64)(q8(a.x) | (q8(a.y) << 8) | (q8(a.z) << 16) | (q8(a.w) << 24))
              | ((u64)(q8(b.x) | (q8(b.y) << 8) | (q8(b.z) << 16) | (q8(b.w) << 24)) << 32);
        residq[i] = p;
    }
}

// i8 MFMA GEMM sim_int = Ri [NB x DD] @ Ci^T [KC x DD] (x256 scale), 256x256
// tile, BK=64 via mfma_i32_16x16x64_i8. Proven R12 structure: register-staged
// 2 tiles ahead, single s_barrier per tile, both-side XOR swizzle, branchless
// packed top-2 epilogue. UNCHANGED.
__global__ __launch_bounds__(512, 2)
void k_simtop2(const char* __restrict__ Ri, const char* __restrict__ Ci,
               Top2* __restrict__ part /* [NB][NTB] */)
{
    __shared__ __align__(16) char As[2][16384];   // [buf][256 rows x 64 B] = 32 KB
    __shared__ __align__(16) char Bs[2][16384];   // 32 KB

    const int tid  = threadIdx.x;
    const int lane = tid & 63;
    const int w    = tid >> 6;        // 0..7
    const int wm   = w >> 2;          // 0..1  (row half)
    const int wn   = w & 3;           // 0..3  (col quarter)

    const int bid = blockIdx.x;
    const int xcd = bid & 7;
    const int idx = bid >> 3;                           // 0..63
    const int row_pan  = (xcd >> 1) * 8 + (idx >> 3);   // 0..31
    const int col_tile = (xcd & 1) * 8 + (idx & 7);     // 0..15
    const int rb0 = row_pan * GBM;
    const int cb0 = col_tile * GBN;

    const int rowA = tid >> 1;
    const int h    = tid & 1;
    const int fr   = (rowA & 3) ^ ((rowA >> 2) & 3);
    const char* gAb = Ri + (size_t)(rb0 + rowA) * 512 + h * 32;
    const char* gBb = Ci + (size_t)(cb0 + rowA) * 512 + h * 32;
    const int wpos0 = rowA * 64 + (((2 * h)     ^ fr) << 4);
    const int wpos1 = rowA * 64 + (((2 * h + 1) ^ fr) << 4);

    const int la = lane & 15, ks = lane >> 4;
    const int fla = (la & 3) ^ ((la >> 2) & 3);
    const int offA = (wm * 128 + la) * 64 + ((ks ^ fla) << 4);
    const int offB = (wn * 64  + la) * 64 + ((ks ^ fla) << 4);

    i32x4 acc[8][4];
    const i32x4 zero = {0, 0, 0, 0};
#pragma unroll
    for (int m = 0; m < 8; ++m)
#pragma unroll
        for (int n = 0; n < 4; ++n) acc[m][n] = zero;

    uint4 eA0, eA1, eB0, eB1;
    uint4 oA0, oA1, oB0, oB1;

#define LOADT(rA0, rA1, rB0, rB1, T) do {                    \
        const char* _pa = gAb + (T) * 64;                    \
        rA0 = *(const uint4*)(_pa);                          \
        rA1 = *(const uint4*)(_pa + 16);                     \
        const char* _pb = gBb + (T) * 64;                    \
        rB0 = *(const uint4*)(_pb);                          \
        rB1 = *(const uint4*)(_pb + 16);                     \
    } while (0)

#define ITER(T, rA0, rA1, rB0, rB1, P) do {                               \
        *(uint4*)(&As[P][0] + wpos0) = rA0;                               \
        *(uint4*)(&As[P][0] + wpos1) = rA1;                               \
        *(uint4*)(&Bs[P][0] + wpos0) = rB0;                               \
        *(uint4*)(&Bs[P][0] + wpos1) = rB1;                               \
        if ((T) + 2 < 8) LOADT(rA0, rA1, rB0, rB1, (T) + 2);              \
        asm volatile("s_waitcnt lgkmcnt(0)" ::: "memory");                \
        __builtin_amdgcn_s_barrier();                                     \
        const char* _rA = &As[P][0];                                      \
        const char* _rB = &Bs[P][0];                                      \
        i32x4 av[8], bv[4];                                               \
        _Pragma("unroll")                                                 \
        for (int m = 0; m < 8; ++m) av[m] = *(const i32x4*)(_rA + offA + m * 1024); \
        _Pragma("unroll")                                                 \
        for (int n = 0; n < 4; ++n) bv[n] = *(const i32x4*)(_rB + offB + n * 1024); \
        _Pragma("unroll")                                                 \
        for (int m = 0; m < 8; ++m)                                       \
            _Pragma("unroll")                                             \
            for (int n = 0; n < 4; ++n)                                   \
                acc[m][n] = __builtin_amdgcn_mfma_i32_16x16x64_i8(av[m], bv[n], acc[m][n], 0, 0, 0); \
    } while (0)

    LOADT(eA0, eA1, eB0, eB1, 0);
    LOADT(oA0, oA1, oB0, oB1, 1);

#pragma unroll 1
    for (int tt = 0; tt < 8; tt += 2) {
        ITER(tt,     eA0, eA1, eB0, eB1, 0);
        ITER(tt + 1, oA0, oA1, oB0, oB1, 1);
    }
#undef ITER
#undef LOADT

    __syncthreads();                           // LDS free; reuse As for merge
    uint2 (*mrg)[4] = (uint2 (*)[4])&As[0][0]; // [256 rows][4 wave-cols] = 8 KB

    // key = ((sim ^ 0x80000000) & ~0x7F) | (127 - l128)
    const int rgrp = lane >> 4;
    const int cidx = lane & 15;
    u32 inv[4];
#pragma unroll
    for (int n = 0; n < 4; ++n)
        inv[n] = (u32)(127 - ((wn & 1) * 64 + n * 16 + cidx));

#pragma unroll
    for (int m = 0; m < 8; ++m) {
#pragma unroll
        for (int j = 0; j < 4; ++j) {
            const u32 p0 = ((((u32)acc[m][0][j]) ^ 0x80000000u) & 0xFFFFFF80u) | inv[0];
            const u32 p1 = ((((u32)acc[m][1][j]) ^ 0x80000000u) & 0xFFFFFF80u) | inv[1];
            const u32 p2 = ((((u32)acc[m][2][j]) ^ 0x80000000u) & 0xFFFFFF80u) | inv[2];
            const u32 p3 = ((((u32)acc[m][3][j]) ^ 0x80000000u) & 0xFFFFFF80u) | inv[3];
            const u32 s1 = umaxu(p0, p1), t1 = uminu(p0, p1);
            const u32 s2 = umaxu(p2, p3), t2 = uminu(p2, p3);
            u32 hi = umaxu(s1, s2);
            u32 lo = umaxu(uminu(s1, s2), umaxu(t1, t2));
#pragma unroll
            for (int off = 1; off < 16; off <<= 1) {
                const u32 oh = (u32)__shfl_xor((int)hi, off);
                const u32 ol = (u32)__shfl_xor((int)lo, off);
                const u32 nh = umaxu(hi, oh);
                lo = umaxu(uminu(hi, oh), umaxu(lo, ol));
                hi = nh;
            }
            if (cidx == 0)
                mrg[wm * 128 + m * 16 + rgrp * 4 + j][wn] = make_uint2(hi, lo);
        }
    }
    __syncthreads();
    if (tid < 256) {   // merge wn pairs -> top-2 per 128-code half
#pragma unroll
        for (int tau = 0; tau < 2; ++tau) {
            const uint2 a = mrg[tid][tau * 2], b = mrg[tid][tau * 2 + 1];
            const u32 hi = umaxu(a.x, b.x);
            const u32 lo = umaxu(uminu(a.x, b.x), umaxu(a.y, b.y));
            Top2 p;
            p.v1 = (float)(int)((hi & 0xFFFFFF80u) ^ 0x80000000u);
            p.i1 = cb0 + tau * 128 + 127 - (int)(hi & 127u);
            p.v2 = (float)(int)((lo & 0xFFFFFF80u) ^ 0x80000000u);
            p.i2 = cb0 + tau * 128 + 127 - (int)(lo & 127u);
            part[(size_t)(rb0 + tid) * NTB + col_tile * 2 + tau] = p;
        }
    }
}

// Refine: ONE WAVE PER ROW, register-resident, zero __syncthreads.
// If chain != nullptr, an ALIGNED fp32 residual mirror lives in ws: reads are
// float4-vectorized (out_stack is odd-aligned -> scalar-only), writes go to
// both chain (vec) and out_stack (scalar, output). Selection semantics
// unchanged: exact fp32 re-dot of candidates within MARGIN_I of int-sim max,
// lowest-index tie-break. grid NB/4 x 256.
__global__ __launch_bounds__(256)
void k_refine(const Top2* __restrict__ part, const float* __restrict__ CB,
              const float* __restrict__ prevBase, size_t prevStride, int vecload,
              const float* __restrict__ X, float* __restrict__ out_q,
              float* __restrict__ stack, float* __restrict__ chain,
              char* __restrict__ residq, float* __restrict__ out_usage,
              float* __restrict__ pl, int layer)
{
    const int lane = threadIdx.x & 63;
    const int b    = blockIdx.x * 4 + (threadIdx.x >> 6);   // row

    const float* pr = prevBase + (size_t)b * prevStride + lane * 8;
    float r[8];
    if (vecload) {
        const float4 a = ((const float4*)pr)[0];
        const float4 c = ((const float4*)pr)[1];
        r[0] = a.x; r[1] = a.y; r[2] = a.z; r[3] = a.w;
        r[4] = c.x; r[5] = c.y; r[6] = c.z; r[7] = c.w;
    } else {
#pragma unroll
        for (int q = 0; q < 8; ++q) r[q] = pr[q];
    }

    // candidates: lane c holds candidate c (tile c>>1, parity c&1)
    const uint4 pp = ((const uint4*)(part + (size_t)b * NTB))[lane >> 1];
    const float cv = (lane & 1) ? __uint_as_float(pp.z) : __uint_as_float(pp.x);
    const int   ci = (lane & 1) ? (int)pp.w : (int)pp.y;

    float mx = cv;
#pragma unroll
    for (int off = 1; off < 64; off <<= 1) mx = fmaxf(mx, __shfl_xor(mx, off));
    const float thr = mx - MARGIN_I;

    u64 mask = __ballot(cv >= thr);
    float bestV = -INFINITY;
    int   bestI = 0x7fffffff;
    while (mask) {
        const int c = __ffsll(mask) - 1;
        mask &= mask - 1;
        const int cidx = __shfl(ci, c);
        const float* cr = CB + (size_t)cidx * DD + lane * 8;
        float p = 0.f;
#pragma unroll
        for (int q = 0; q < 8; ++q) p = fmaf(r[q], cr[q], p);
#pragma unroll
        for (int off = 32; off >= 1; off >>= 1) p += __shfl_xor(p, off);
        if (p > bestV || (p == bestV && cidx < bestI)) { bestV = p; bestI = cidx; }
    }
    if (lane == 0) out_usage[layer * KC + bestI] = 1.0f;

    const float* cb = CB + (size_t)bestI * DD + lane * 8;
    float rn[8];
    float ss = 0.f;
#pragma unroll
    for (int q = 0; q < 8; ++q) { rn[q] = r[q] - cb[q]; ss = fmaf(rn[q], rn[q], ss); }

    float* sp = stack + ((size_t)b * NL + layer) * DD + lane * 8;  // odd-aligned -> scalar
#pragma unroll
    for (int q = 0; q < 8; ++q) sp[q] = rn[q];

    if (chain) {   // aligned mirror for next layer's vectorized read
        float4 c0, c1;
        c0.x = rn[0]; c0.y = rn[1]; c0.z = rn[2]; c0.w = rn[3];
        c1.x = rn[4]; c1.y = rn[5]; c1.z = rn[6]; c1.w = rn[7];
        float4* cp = (float4*)(chain + (size_t)b * DD + lane * 8);
        cp[0] = c0; cp[1] = c1;
    }

    // i8 mirror for next layer's GEMM (8 B per lane, contiguous)
    u64 pq = (u64)(q8(rn[0]) | (q8(rn[1]) << 8) | (q8(rn[2]) << 16) | (q8(rn[3]) << 24))
           | ((u64)(q8(rn[4]) | (q8(rn[5]) << 8) | (q8(rn[6]) << 16) | (q8(rn[7]) << 24)) << 32);
    *(u64*)(residq + (size_t)b * DD + lane * 8) = pq;

    if (layer == NL - 1) {
        const float* xr = X + (size_t)b * DD + lane * 8;
        float4 q0, q1;
        q0.x = xr[0] - rn[0]; q0.y = xr[1] - rn[1];
        q0.z = xr[2] - rn[2]; q0.w = xr[3] - rn[3];
        q1.x = xr[4] - rn[4]; q1.y = xr[5] - rn[5];
        q1.z = xr[6] - rn[6]; q1.w = xr[7] - rn[7];
        float4* qp = (float4*)(out_q + (size_t)b * DD + lane * 8);
        qp[0] = q0; qp[1] = q1;
    }

#pragma unroll
    for (int off = 32; off >= 1; off >>= 1) ss += __shfl_xor(ss, off);
    if (lane == 0) pl[(size_t)layer * NB + b] = ss;
}

__global__ __launch_bounds__(256)
void k_finalize(const float* __restrict__ pl, const double* __restrict__ cq,
                int ncq, float* __restrict__ out_loss)
{
    __shared__ double red[256];
    const int tid = threadIdx.x;
    double s = 0.0;
    for (int i = tid; i < NL * NB; i += 256) s += (double)pl[i];
    double s2 = 0.0;
    for (int i = tid; i < ncq; i += 256) s2 += cq[i];
    red[tid] = s / ((double)NB * DD) + 0.01 * (s2 / ((double)NL * KC));
    __syncthreads();
    for (int st = 128; st > 0; st >>= 1) {
        if (tid < st) red[tid] += red[tid + st];
        __syncthreads();
    }
    if (tid == 0) out_loss[0] = (float)(red[0] / (double)DD);
}

extern "C" void kernel_launch(void* const* d_in, const int* in_sizes, int n_in,
                              void* d_out, int out_size, void* d_ws, size_t ws_size,
                              hipStream_t stream)
{
    (void)in_sizes; (void)n_in; (void)out_size;
    const float* x  = (const float*)d_in[0];
    // d_in[1] = temperature: positive scale, argmax-invariant, soft path cancels -> unused
    const float* cb = (const float*)d_in[2];

    float* out       = (float*)d_out;
    float* out_q     = out;                                   // [NB, DD]
    float* out_loss  = out + (size_t)NB * DD;                 // [1]
    float* out_stack = out_loss + 1;                          // [NB, NL, DD] (fp32 residual chain, odd-aligned)
    float* out_usage = out_stack + (size_t)NB * NL * DD;      // [NL, KC]

    char* ws = (char*)d_ws;
    Top2*   part   = (Top2*)ws;                               // 4 MB @ 0
    char*   residq = ws + ((size_t)4 << 20);                  // 4 MB i8 residual mirror
    char*   cbq    = ws + ((size_t)8 << 20);                  // 8 MB i8 codebooks (all layers)
    float*  pl     = (float*)(ws + ((size_t)16 << 20));       // 128 KB loss partials
    double* cq     = (double*)(ws + ((size_t)16 << 20) + 131072 + 256); // 4096 doubles
    float*  chain  = (ws_size >= ((size_t)34 << 20))
                   ? (float*)(ws + ((size_t)17 << 20)) : nullptr; // 16 MB aligned fp32 chain

    k_cvt_all<<<6144, 256, 0, stream>>>(x, cb, (u64*)residq, (u64*)cbq, cq, out_usage);

    for (int l = 0; l < NL; ++l) {
        const float* cbl = cb + (size_t)l * KC * DD;
        k_simtop2<<<512, 512, 0, stream>>>(residq, cbq + (size_t)l * KC * DD, part);
        const float* prevBase;
        size_t prevStride;
        int vec;
        if (l == 0)            { prevBase = x;     prevStride = DD;               vec = 1; }
        else if (chain)        { prevBase = chain; prevStride = DD;               vec = 1; }
        else                   { prevBase = out_stack + (size_t)(l - 1) * DD;
                                 prevStride = (size_t)NL * DD;                    vec = 0; }
        k_refine<<<NB / 4, 256, 0, stream>>>(part, cbl, prevBase, prevStride, vec, x,
                                             out_q, out_stack, chain, residq,
                                             out_usage, pl, l);
    }
    k_finalize<<<1, 256, 0, stream>>>(pl, cq, 4096, out_loss);
}

// Round 16
// 253.895 us; speedup vs baseline: 1.0305x; 1.0305x over previous
//
#include <hip/hip_runtime.h>
#include <math.h>

#define NB 8192     // batch rows
#define DD 512      // hidden dim
#define KC 4096     // codebook size
#define NL 4        // layers

#define NTB 32        // part[] column tiles (128 codes each)
#define MARGIN_I 2048.0f // refine margin, int-sim units (256 x true; >10 sigma of i8 noise)
#define QS 16.0f      // i8 quantization scale

#define GBM 256
#define GBN 256

typedef int    i32x4 __attribute__((ext_vector_type(4)));
typedef unsigned short u16;
typedef unsigned int   u32;
typedef unsigned long long u64;

struct Top2 { float v1; int i1; float v2; int i2; };

__device__ __forceinline__ u32 umaxu(u32 a, u32 b) { return a > b ? a : b; }
__device__ __forceinline__ u32 uminu(u32 a, u32 b) { return a < b ? a : b; }

__device__ __forceinline__ u32 q8(float f) {   // fp32 -> signed i8 (byte), scale QS
    int v = (int)rintf(f * QS);
    v = v < -127 ? -127 : (v > 127 ? 127 : v);
    return (u32)(v & 0xFF);
}

// Fused front-end: blocks [0,4096) convert codebooks fp32->i8 + cbsq partials
// (+ first 64 blocks zero out_usage); blocks [4096,6144) convert x -> residq.
__global__ __launch_bounds__(256)
void k_cvt_all(const float* __restrict__ x, const float* __restrict__ cb,
               u64* __restrict__ residq, u64* __restrict__ cbq,
               double* __restrict__ cq, float* __restrict__ usage)
{
    const int bid = blockIdx.x;
    if (bid < 4096) {
        __shared__ double red[256];
        const int i = bid * 256 + threadIdx.x;
        if (bid < 64) {   // 64*256 threads x 4 floats = 65536 = NL*KC
            const float4 z = {0.f, 0.f, 0.f, 0.f};
            ((float4*)usage)[i] = z;
        }
        const float4 a = ((const float4*)cb)[i * 2];
        const float4 b = ((const float4*)cb)[i * 2 + 1];
        u64 p = (u64)(q8(a.x) | (q8(a.y) << 8) | (q8(a.z) << 16) | (q8(a.w) << 24))
              | ((u64)(q8(b.x) | (q8(b.y) << 8) | (q8(b.z) << 16) | (q8(b.w) << 24)) << 32);
        cbq[i] = p;
        red[threadIdx.x] = (double)a.x * a.x + (double)a.y * a.y + (double)a.z * a.z
                         + (double)a.w * a.w + (double)b.x * b.x + (double)b.y * b.y
                         + (double)b.z * b.z + (double)b.w * b.w;
        __syncthreads();
        for (int st = 128; st > 0; st >>= 1) {
            if (threadIdx.x < st) red[threadIdx.x] += red[threadIdx.x + st];
            __syncthreads();
        }
        if (threadIdx.x == 0) cq[bid] = red[0];
    } else {
        const int i = (bid - 4096) * 256 + threadIdx.x;   // exact: NB*DD/8 = 524288
        const float4 a = ((const float4*)x)[i * 2];
        const float4 b = ((const float4*)x)[i * 2 + 1];
        u64 p = (u64)(q8(a.x) | (q8(a.y) << 8) | (q8(a.z) << 16) | (q8(a.w) << 24))
              | ((u64)(q8(b.x) | (q8(b.y) << 8) | (q8(b.z) << 16) | (q8(b.w) << 24)) << 32);
        residq[i] = p;
    }
}

// i8 MFMA GEMM sim_int = Ri [NB x DD] @ Ci^T [KC x DD] (x256 scale), 256x256
// tile, BK=64, mfma_i32_16x16x64_i8. Reads-first iteration order --
// {barrier; ds_read(T); ds_write(T+1); global-load(T+3); MFMA; lgkm0}.
// Refill ledger (R15 bug fixed -- o MUST be refilled with tile 7 at T=4):
//   e loads tiles {0,2,4,6} at {pro,pro,T1,T3}; publishes {0(pro),2,4,6} at {pro,T1,T3,T5}
//   o loads tiles {1,3,5,7} at {pro,T0,T2,T4}; publishes {1,3,5,7} at {T0,T2,T4,T6}
// Write/read safety: each iter's end lgkm0 + next iter's barrier fence both
// read-after-write (published tile) and write-after-read (recycled buffer).
__global__ __launch_bounds__(512, 2)
void k_simtop2(const char* __restrict__ Ri, const char* __restrict__ Ci,
               Top2* __restrict__ part /* [NB][NTB] */)
{
    __shared__ __align__(16) char As[2][16384];   // [buf][256 rows x 64 B] = 32 KB
    __shared__ __align__(16) char Bs[2][16384];   // 32 KB

    const int tid  = threadIdx.x;
    const int lane = tid & 63;
    const int w    = tid >> 6;        // 0..7
    const int wm   = w >> 2;          // 0..1  (row half)
    const int wn   = w & 3;           // 0..3  (col quarter)

    const int bid = blockIdx.x;
    const int xcd = bid & 7;
    const int idx = bid >> 3;                           // 0..63
    const int row_pan  = (xcd >> 1) * 8 + (idx >> 3);   // 0..31
    const int col_tile = (xcd & 1) * 8 + (idx & 7);     // 0..15
    const int rb0 = row_pan * GBM;
    const int cb0 = col_tile * GBN;

    const int rowA = tid >> 1;
    const int h    = tid & 1;
    const int fr   = (rowA & 3) ^ ((rowA >> 2) & 3);
    const char* gAb = Ri + (size_t)(rb0 + rowA) * 512 + h * 32;
    const char* gBb = Ci + (size_t)(cb0 + rowA) * 512 + h * 32;
    const int wpos0 = rowA * 64 + (((2 * h)     ^ fr) << 4);
    const int wpos1 = rowA * 64 + (((2 * h + 1) ^ fr) << 4);

    const int la = lane & 15, ks = lane >> 4;
    const int fla = (la & 3) ^ ((la >> 2) & 3);
    const int offA = (wm * 128 + la) * 64 + ((ks ^ fla) << 4);
    const int offB = (wn * 64  + la) * 64 + ((ks ^ fla) << 4);

    i32x4 acc[8][4];
    const i32x4 zero = {0, 0, 0, 0};
#pragma unroll
    for (int m = 0; m < 8; ++m)
#pragma unroll
        for (int n = 0; n < 4; ++n) acc[m][n] = zero;

    uint4 eA0, eA1, eB0, eB1;   // even-tile staging regs
    uint4 oA0, oA1, oB0, oB1;   // odd-tile staging regs

#define LOADT(rA0, rA1, rB0, rB1, T) do {                    \
        const char* _pa = gAb + (T) * 64;                    \
        rA0 = *(const uint4*)(_pa);                          \
        rA1 = *(const uint4*)(_pa + 16);                     \
        const char* _pb = gBb + (T) * 64;                    \
        rB0 = *(const uint4*)(_pb);                          \
        rB1 = *(const uint4*)(_pb + 16);                     \
    } while (0)

#define WRITET(rA0, rA1, rB0, rB1, P) do {                   \
        *(uint4*)(&As[P][0] + wpos0) = rA0;                  \
        *(uint4*)(&As[P][0] + wpos1) = rA1;                  \
        *(uint4*)(&Bs[P][0] + wpos0) = rB0;                  \
        *(uint4*)(&Bs[P][0] + wpos1) = rB1;                  \
    } while (0)

    // ITER(T): compute tile T from buf[T&1]; publish tile T+1 (regset (T+1)&1)
    // into buf[(T+1)&1]; refill that regset with tile T+3 (if DOL).
#define ITER(T, wA0, wA1, wB0, wB1, DOW, DOL) do {                        \
        __builtin_amdgcn_s_barrier();                                     \
        __builtin_amdgcn_sched_barrier(0);                                \
        const char* _rA = &As[(T) & 1][0];                                \
        const char* _rB = &Bs[(T) & 1][0];                                \
        i32x4 av[8], bv[4];                                               \
        _Pragma("unroll")                                                 \
        for (int m = 0; m < 8; ++m) av[m] = *(const i32x4*)(_rA + offA + m * 1024); \
        _Pragma("unroll")                                                 \
        for (int n = 0; n < 4; ++n) bv[n] = *(const i32x4*)(_rB + offB + n * 1024); \
        if (DOW) WRITET(wA0, wA1, wB0, wB1, ((T) + 1) & 1);               \
        if (DOL) LOADT(wA0, wA1, wB0, wB1, (T) + 3);                      \
        _Pragma("unroll")                                                 \
        for (int m = 0; m < 8; ++m)                                       \
            _Pragma("unroll")                                             \
            for (int n = 0; n < 4; ++n)                                   \
                acc[m][n] = __builtin_amdgcn_mfma_i32_16x16x64_i8(av[m], bv[n], acc[m][n], 0, 0, 0); \
        asm volatile("s_waitcnt lgkmcnt(0)" ::: "memory");                \
    } while (0)

    // prologue: e<-0, o<-1; publish tile0 -> buf0; e<-2
    LOADT(eA0, eA1, eB0, eB1, 0);
    LOADT(oA0, oA1, oB0, oB1, 1);
    WRITET(eA0, eA1, eB0, eB1, 0);
    LOADT(eA0, eA1, eB0, eB1, 2);
    asm volatile("s_waitcnt lgkmcnt(0)" ::: "memory");

    ITER(0, oA0, oA1, oB0, oB1, 1, 1);   // publish o=1 -> buf1; o <- 3
    ITER(1, eA0, eA1, eB0, eB1, 1, 1);   // publish e=2 -> buf0; e <- 4
    ITER(2, oA0, oA1, oB0, oB1, 1, 1);   // publish o=3 -> buf1; o <- 5
    ITER(3, eA0, eA1, eB0, eB1, 1, 1);   // publish e=4 -> buf0; e <- 6
    ITER(4, oA0, oA1, oB0, oB1, 1, 1);   // publish o=5 -> buf1; o <- 7  (R15 bug: was DOL=0)
    ITER(5, eA0, eA1, eB0, eB1, 1, 0);   // publish e=6 -> buf0
    ITER(6, oA0, oA1, oB0, oB1, 1, 0);   // publish o=7 -> buf1
    ITER(7, oA0, oA1, oB0, oB1, 0, 0);   // compute tile7, no publish
#undef ITER
#undef WRITET
#undef LOADT

    __syncthreads();                           // LDS free; reuse As for merge
    uint2 (*mrg)[4] = (uint2 (*)[4])&As[0][0]; // [256 rows][4 wave-cols] = 8 KB

    // key = ((sim ^ 0x80000000) & ~0x7F) | (127 - l128)
    const int rgrp = lane >> 4;
    const int cidx = lane & 15;
    u32 inv[4];
#pragma unroll
    for (int n = 0; n < 4; ++n)
        inv[n] = (u32)(127 - ((wn & 1) * 64 + n * 16 + cidx));

#pragma unroll
    for (int m = 0; m < 8; ++m) {
#pragma unroll
        for (int j = 0; j < 4; ++j) {
            const u32 p0 = ((((u32)acc[m][0][j]) ^ 0x80000000u) & 0xFFFFFF80u) | inv[0];
            const u32 p1 = ((((u32)acc[m][1][j]) ^ 0x80000000u) & 0xFFFFFF80u) | inv[1];
            const u32 p2 = ((((u32)acc[m][2][j]) ^ 0x80000000u) & 0xFFFFFF80u) | inv[2];
            const u32 p3 = ((((u32)acc[m][3][j]) ^ 0x80000000u) & 0xFFFFFF80u) | inv[3];
            const u32 s1 = umaxu(p0, p1), t1 = uminu(p0, p1);
            const u32 s2 = umaxu(p2, p3), t2 = uminu(p2, p3);
            u32 hi = umaxu(s1, s2);
            u32 lo = umaxu(uminu(s1, s2), umaxu(t1, t2));
#pragma unroll
            for (int off = 1; off < 16; off <<= 1) {
                const u32 oh = (u32)__shfl_xor((int)hi, off);
                const u32 ol = (u32)__shfl_xor((int)lo, off);
                const u32 nh = umaxu(hi, oh);
                lo = umaxu(uminu(hi, oh), umaxu(lo, ol));
                hi = nh;
            }
            if (cidx == 0)
                mrg[wm * 128 + m * 16 + rgrp * 4 + j][wn] = make_uint2(hi, lo);
        }
    }
    __syncthreads();
    {   // all 512 threads: row = tid&255, tau = tid>>8
        const int row = tid & 255, tau = tid >> 8;
        const uint2 a = mrg[row][tau * 2], b = mrg[row][tau * 2 + 1];
        const u32 hi = umaxu(a.x, b.x);
        const u32 lo = umaxu(uminu(a.x, b.x), umaxu(a.y, b.y));
        Top2 p;
        p.v1 = (float)(int)((hi & 0xFFFFFF80u) ^ 0x80000000u);
        p.i1 = cb0 + tau * 128 + 127 - (int)(hi & 127u);
        p.v2 = (float)(int)((lo & 0xFFFFFF80u) ^ 0x80000000u);
        p.i2 = cb0 + tau * 128 + 127 - (int)(lo & 127u);
        part[(size_t)(rb0 + row) * NTB + col_tile * 2 + tau] = p;
    }
}

// Refine: ONE WAVE PER ROW, register-resident, zero __syncthreads (R13 exact).
__global__ __launch_bounds__(256)
void k_refine(const Top2* __restrict__ part, const float* __restrict__ CB,
              const float* __restrict__ prevBase, size_t prevStride,
              const float* __restrict__ X, float* __restrict__ out_q,
              float* __restrict__ stack, char* __restrict__ residq,
              float* __restrict__ out_usage, float* __restrict__ pl,
              int layer)
{
    const int lane = threadIdx.x & 63;
    const int b    = blockIdx.x * 4 + (threadIdx.x >> 6);   // row

    const float* pr = prevBase + (size_t)b * prevStride + lane * 8;
    float r[8];
#pragma unroll
    for (int q = 0; q < 8; ++q) r[q] = pr[q];

    // candidates: lane c holds candidate c (tile c>>1, parity c&1)
    const uint4 pp = ((const uint4*)(part + (size_t)b * NTB))[lane >> 1];
    const float cv = (lane & 1) ? __uint_as_float(pp.z) : __uint_as_float(pp.x);
    const int   ci = (lane & 1) ? (int)pp.w : (int)pp.y;

    float mx = cv;
#pragma unroll
    for (int off = 1; off < 64; off <<= 1) mx = fmaxf(mx, __shfl_xor(mx, off));
    const float thr = mx - MARGIN_I;

    u64 mask = __ballot(cv >= thr);
    float bestV = -INFINITY;
    int   bestI = 0x7fffffff;
    while (mask) {
        const int c = __ffsll(mask) - 1;
        mask &= mask - 1;
        const int cidx = __shfl(ci, c);
        const float* cr = CB + (size_t)cidx * DD + lane * 8;
        float p = 0.f;
#pragma unroll
        for (int q = 0; q < 8; ++q) p = fmaf(r[q], cr[q], p);
#pragma unroll
        for (int off = 32; off >= 1; off >>= 1) p += __shfl_xor(p, off);
        if (p > bestV || (p == bestV && cidx < bestI)) { bestV = p; bestI = cidx; }
    }
    if (lane == 0) out_usage[layer * KC + bestI] = 1.0f;

    const float* cb = CB + (size_t)bestI * DD + lane * 8;
    float rn[8];
    float ss = 0.f;
#pragma unroll
    for (int q = 0; q < 8; ++q) { rn[q] = r[q] - cb[q]; ss = fmaf(rn[q], rn[q], ss); }

    float* sp = stack + ((size_t)b * NL + layer) * DD + lane * 8;  // odd-aligned -> scalar
#pragma unroll
    for (int q = 0; q < 8; ++q) sp[q] = rn[q];

    // i8 mirror for next layer's GEMM (8 B per lane, contiguous)
    u64 pq = (u64)(q8(rn[0]) | (q8(rn[1]) << 8) | (q8(rn[2]) << 16) | (q8(rn[3]) << 24))
           | ((u64)(q8(rn[4]) | (q8(rn[5]) << 8) | (q8(rn[6]) << 16) | (q8(rn[7]) << 24)) << 32);
    *(u64*)(residq + (size_t)b * DD + lane * 8) = pq;

    if (layer == NL - 1) {
        const float* xr = X + (size_t)b * DD + lane * 8;
        float4 q0, q1;
        q0.x = xr[0] - rn[0]; q0.y = xr[1] - rn[1];
        q0.z = xr[2] - rn[2]; q0.w = xr[3] - rn[3];
        q1.x = xr[4] - rn[4]; q1.y = xr[5] - rn[5];
        q1.z = xr[6] - rn[6]; q1.w = xr[7] - rn[7];
        float4* qp = (float4*)(out_q + (size_t)b * DD + lane * 8);
        qp[0] = q0; qp[1] = q1;
    }

#pragma unroll
    for (int off = 32; off >= 1; off >>= 1) ss += __shfl_xor(ss, off);
    if (lane == 0) pl[(size_t)layer * NB + b] = ss;
}

__global__ __launch_bounds__(256)
void k_finalize(const float* __restrict__ pl, const double* __restrict__ cq,
                int ncq, float* __restrict__ out_loss)
{
    __shared__ double red[256];
    const int tid = threadIdx.x;
    double s = 0.0;
    for (int i = tid; i < NL * NB; i += 256) s += (double)pl[i];
    double s2 = 0.0;
    for (int i = tid; i < ncq; i += 256) s2 += cq[i];
    red[tid] = s / ((double)NB * DD) + 0.01 * (s2 / ((double)NL * KC));
    __syncthreads();
    for (int st = 128; st > 0; st >>= 1) {
        if (tid < st) red[tid] += red[tid + st];
        __syncthreads();
    }
    if (tid == 0) out_loss[0] = (float)(red[0] / (double)DD);
}

extern "C" void kernel_launch(void* const* d_in, const int* in_sizes, int n_in,
                              void* d_out, int out_size, void* d_ws, size_t ws_size,
                              hipStream_t stream)
{
    (void)in_sizes; (void)n_in; (void)out_size; (void)ws_size;
    const float* x  = (const float*)d_in[0];
    // d_in[1] = temperature: positive scale, argmax-invariant, soft path cancels -> unused
    const float* cb = (const float*)d_in[2];

    float* out       = (float*)d_out;
    float* out_q     = out;                                   // [NB, DD]
    float* out_loss  = out + (size_t)NB * DD;                 // [1]
    float* out_stack = out_loss + 1;                          // [NB, NL, DD] (fp32 residual chain, odd-aligned)
    float* out_usage = out_stack + (size_t)NB * NL * DD;      // [NL, KC]

    char* ws = (char*)d_ws;
    Top2*   part   = (Top2*)ws;                               // 4 MB @ 0
    char*   residq = ws + ((size_t)4 << 20);                  // 4 MB i8 residual mirror
    char*   cbq    = ws + ((size_t)8 << 20);                  // 8 MB i8 codebooks (all layers)
    float*  pl     = (float*)(ws + ((size_t)16 << 20));       // 128 KB loss partials
    double* cq     = (double*)(ws + ((size_t)16 << 20) + 131072 + 256); // 4096 doubles

    k_cvt_all<<<6144, 256, 0, stream>>>(x, cb, (u64*)residq, (u64*)cbq, cq, out_usage);

    for (int l = 0; l < NL; ++l) {
        const float* cbl = cb + (size_t)l * KC * DD;
        k_simtop2<<<512, 512, 0, stream>>>(residq, cbq + (size_t)l * KC * DD, part);
        const float* prevBase = (l == 0) ? x : (out_stack + (size_t)(l - 1) * DD);
        const size_t prevStride = (l == 0) ? (size_t)DD : (size_t)NL * DD;
        k_refine<<<NB / 4, 256, 0, stream>>>(part, cbl, prevBase, prevStride, x, out_q,
                                             out_stack, residq, out_usage, pl, l);
    }
    k_finalize<<<1, 256, 0, stream>>>(pl, cq, 4096, out_loss);
}